// Round 1
// 173.795 us; speedup vs baseline: 1.0095x; 1.0095x over previous
//
#include <hip/hip_runtime.h>

// ---------------------------------------------------------------------------
// Factorized algorithm (verified rounds 2-11). Shells = ascending r2 rank:
//   r2 in {0,1,2,3,4,5,6,8,9,12} -> shell 0..9
// y[l][r][d][z] = sum_{taps t in shell r} sph_l[t] * x[d, xo+i, yo+j, z+kk]
// conv_r[s,e,z] = sum_{r,d} wfull[wig_w[s], r, e, d] * y[wig_b[s]][r][d][z]
// s=0:(w,b)=(0,0); s=1..9: w=1+(s-1)/3, b=1+(s-1)%3
// Round 13: bank-conflict elimination on top of r12.
//  - Y2 permuted layout: word(k,yo,z,l) = k*192 + perm(yo,z)*4 + l,
//    perm = ((z&1)*3 + (zt>>1))*8 + (zt&1)*4 + yo  (zt = z>>1, bijective).
//    Stage-2 b128 reads: bank-group = (zt&1)*4+yo -> 8 distinct -> conflict-
//    free (was 2-way: yo*48 aliased yo/yo+2). Writes drop 6-way -> 3-way.
//  - XT staging decode: j in low bits -> b128 write bank-group (5j+zq)%8,
//    5j%8 is a permutation -> consecutive 8 lanes conflict-free (was 8-way).
// ---------------------------------------------------------------------------

// prep: W2[p8][k20][e16][w4] (k=2r+di, d=2p+di) + CT2[l][25][8]
__global__ void prep_kernel(const float* __restrict__ weight,     // (4,9,16,16)
                            const float* __restrict__ zw,         // (16,16)
                            const float* __restrict__ bf,         // (4,10,125)
                            float* __restrict__ W2,               // 10240 f32
                            float* __restrict__ TAB)              // 800 f32
{
    int t = blockIdx.x * 256 + threadIdx.x;
    if (t < 10240) {
        int w = t & 3;
        int e = (t >> 2) & 15;
        int k = (t >> 6) % 20;
        int p = t / 1280;
        int r = k >> 1, di = k & 1, d = 2 * p + di;
        float v;
        if (r == 0) v = (w == 0) ? zw[e * 16 + d] : 0.f;
        else        v = weight[((w * 9 + (r - 1)) * 16 + e) * 16 + d];
        W2[t] = v;
    } else if (t < 10240 + 800) {
        int q = t - 10240;           // q = (l*25 + slice)*8 + kk
        int l = q / 200;
        int rem = q % 200;
        int slice = rem / 8, kk = rem % 8;
        float s = 0.f;
        if (kk < 5) {
            int tap = slice * 5 + kk;
            for (int r = 0; r < 10; ++r) s += bf[(l * 10 + r) * 125 + tap];
        }
        TAB[q] = s;                  // sph_l[tap] (masks partition the cube)
    }
}

__global__ __launch_bounds__(192) void fused_kernel(
    const float* __restrict__ x,    // (2,16,40,40,40)
    const float* __restrict__ W2,   // [p][k20][e16][w4]
    const float* __restrict__ TAB,  // CT2 [l][25][8]
    const float* __restrict__ g,    // (27,10)
    const float* __restrict__ w_i,  // (3,)
    const float* __restrict__ bias, // (16,)
    float* __restrict__ out)        // (2,16,36,36,36)
{
    __shared__ float Y2[3840];      // [k20][perm(yo,z)][l4] permuted layout
    __shared__ float CT[800];       // [l4][25][8]
    __shared__ float XT[1600];      // [di2][i5][j8] rows of 20 (16 z used)

    const int tid = threadIdx.x;

    // XCD-chunked swizzle: 1944 blocks = 8 XCDs x 243 contiguous wgids
    const int bid  = blockIdx.x;
    const int wgid = (bid & 7) * 243 + (bid >> 3);
    const int xo  = wgid % 36;
    const int yoq = (wgid / 36) % 9;
    const int zs  = (wgid / 324) % 3;   // z base = 12*zs
    const int bb  = wgid / 972;

    // stage-1 decode (di2, l4, yo4, zt6): 2 z per thread
    const int s_zt = tid % 6;
    const int s_yo = (tid / 6) & 3;
    const int s_l  = (tid / 24) & 3;
    const int s_di = tid / 96;
    // stage-2 decode (e8, yo4, zt6): e = 2*c_e+{0,1}, z = 2*c_zt+{0,1}
    const int c_e  = tid & 7;
    const int c_yo = (tid >> 3) & 3;
    const int c_zt = tid / 32;

    for (int idx = tid; idx < 800; idx += 192) CT[idx] = TAB[idx];

    constexpr int RANKT[13] = {0, 1, 2, 3, 4, 5, 6, 0, 7, 8, 0, 0, 9};

    float acc[10][2][2];   // [s][e-sub][z] = 40 regs
    #pragma unroll
    for (int s = 0; s < 10; ++s)
        #pragma unroll
        for (int ee = 0; ee < 2; ++ee) { acc[s][ee][0] = 0.f; acc[s][ee][1] = 0.f; }

    const float* ct = CT + s_l * 200;

    // Y2 permuted bases:
    //   write (stage-1): z0 = 2*s_zt -> perm0 = (s_zt>>1)*8 + (s_zt&1)*4 + s_yo
    //                    word = k*192 + perm0*4 + s_l  (z1 = z0+1 at +96)
    //   read  (stage-2): same perm with (c_zt, c_yo); f4 over l at +0 / +96
    const int wbase = (((s_zt >> 1) * 8 + (s_zt & 1) * 4 + s_yo) << 2) + s_l;
    const int yb0   = (((c_zt >> 1) * 8 + (c_zt & 1) * 4 + c_yo) << 2);

    // ---- XT staging geometry: 320 float4 per phase, 2 slots per thread ----
    // decode: j in LOW bits -> conflict-free b128 LDS writes (group 5j+zq)
    const int idx0 = tid;
    const int idx1 = tid + 192;
    const bool has1 = idx1 < 320;
    const int j0 = idx0 & 7, zq0 = (idx0 >> 3) & 3, i0 = (idx0 >> 5) % 5, di0 = idx0 / 160;
    const int j1 = idx1 & 7, zq1 = (idx1 >> 3) & 3, i1 = (idx1 >> 5) % 5, di1 = idx1 / 160;
    const int xt0 = ((di0 * 5 + i0) * 8 + j0) * 20 + 4 * zq0;
    const int xt1 = ((di1 * 5 + i1) * 8 + j1) * 20 + 4 * zq1;
    const float* gsrc0 = x + ((((bb * 16 + di0) * 40 + xo + i0) * 40 + yoq * 4 + j0) * 40
                              + zs * 12 + 4 * zq0);
    const float* gsrc1 = x + ((((bb * 16 + di1) * 40 + xo + i1) * 40 + yoq * 4 + j1) * 40
                              + zs * 12 + 4 * zq1);

    // prologue: XT(0) + issue loads for phase 1
    {
        float4 a = *(const float4*)gsrc0;
        float4 b = has1 ? *(const float4*)gsrc1 : make_float4(0.f, 0.f, 0.f, 0.f);
        *(float4*)(XT + xt0) = a;
        if (has1) *(float4*)(XT + xt1) = b;
    }
    gsrc0 += 128000;
    float4 pre0 = *(const float4*)gsrc0;
    float4 pre1 = make_float4(0.f, 0.f, 0.f, 0.f);
    if (has1) { gsrc1 += 128000; pre1 = *(const float4*)gsrc1; }

    for (int p = 0; p < 8; ++p) {
        __syncthreads();   // A: XT(p) ready; Y2 free (stage-2(p-1) done); CT staged
        // ---- stage 1: shell conv for d = 2p+s_di, l = s_l, 2 z (from XT) ----
        {
            float yreg[10][2];
            #pragma unroll
            for (int r = 0; r < 10; ++r) { yreg[r][0] = 0.f; yreg[r][1] = 0.f; }

            const float* xt = XT + s_di * 800;
            #pragma unroll
            for (int i = 0; i < 5; ++i) {
                #pragma unroll
                for (int j = 0; j < 5; ++j) {
                    const float* row = xt + (i * 8 + s_yo + j) * 20 + 2 * s_zt;
                    const float2 a  = *(const float2*)(row);
                    const float2 b2 = *(const float2*)(row + 2);
                    const float2 d2 = *(const float2*)(row + 4);
                    const float xv[6] = {a.x, a.y, b2.x, b2.y, d2.x, d2.y};
                    const float* cs = ct + (i * 5 + j) * 8;
                    const float4 c03 = *(const float4*)cs;   // one b128
                    const float  c4v = cs[4];                // one b32
                    #pragma unroll
                    for (int kk = 0; kk < 5; ++kk) {
                        const int r2 = (i - 2) * (i - 2) + (j - 2) * (j - 2) + (kk - 2) * (kk - 2);
                        const int r  = RANKT[r2];            // compile-time
                        const float cc = (kk == 0) ? c03.x : (kk == 1) ? c03.y :
                                         (kk == 2) ? c03.z : (kk == 3) ? c03.w : c4v;
                        yreg[r][0] = fmaf(cc, xv[kk + 0], yreg[r][0]);
                        yreg[r][1] = fmaf(cc, xv[kk + 1], yreg[r][1]);
                    }
                }
            }
            #pragma unroll
            for (int r = 0; r < 10; ++r) {
                // permuted Y2: word = k*192 + perm0*4 + l ; z1 at +96
                const int wb = (2 * r + s_di) * 192 + wbase;
                Y2[wb]      = yreg[r][0];    // fused into ds_write2_b32
                Y2[wb + 96] = yreg[r][1];
            }
        }
        __syncthreads();   // B: Y2 ready; XT(p) readers done
        // ---- write XT(p+1) from prefetched regs; issue loads for p+2 ----
        if (p < 7) {
            *(float4*)(XT + xt0) = pre0;
            if (has1) *(float4*)(XT + xt1) = pre1;
            if (p < 6) {
                gsrc0 += 128000;
                pre0 = *(const float4*)gsrc0;    // lands during stage2(p)+stage1(p+1)
                if (has1) { gsrc1 += 128000; pre1 = *(const float4*)gsrc1; }
            }
        }
        // ---- stage 2 (E=2): acc[s][ee][z] += wfull * y; 2x b128 per k ----
        {
            const float* W2p = W2 + p * 1280 + c_e * 8;   // e0 = 2*c_e
            #pragma unroll
            for (int k = 0; k < 20; ++k) {
                const float4 wv0 = *(const float4*)(W2p + k * 64);
                const float4 wv1 = *(const float4*)(W2p + k * 64 + 4);
                const float* yb = Y2 + k * 192 + yb0;
                const float4 yz0 = *(const float4*)(yb);       // l0..3 at z0
                const float4 yz1 = *(const float4*)(yb + 96);  // l0..3 at z1
                {   // b = 0 pairs only with w = 0 -> s = 0
                    acc[0][0][0] = fmaf(wv0.x, yz0.x, acc[0][0][0]);
                    acc[0][0][1] = fmaf(wv0.x, yz1.x, acc[0][0][1]);
                    acc[0][1][0] = fmaf(wv1.x, yz0.x, acc[0][1][0]);
                    acc[0][1][1] = fmaf(wv1.x, yz1.x, acc[0][1][1]);
                }
                #pragma unroll
                for (int b = 1; b < 4; ++b) {
                    const float y0 = (b == 1) ? yz0.y : (b == 2) ? yz0.z : yz0.w;
                    const float y1 = (b == 1) ? yz1.y : (b == 2) ? yz1.z : yz1.w;
                    #pragma unroll
                    for (int w = 1; w < 4; ++w) {
                        const int s = 1 + (w - 1) * 3 + (b - 1);
                        const float w0 = (w == 1) ? wv0.y : ((w == 2) ? wv0.z : wv0.w);
                        const float w1 = (w == 1) ? wv1.y : ((w == 2) ? wv1.z : wv1.w);
                        acc[s][0][0] = fmaf(w0, y0, acc[s][0][0]);
                        acc[s][0][1] = fmaf(w0, y1, acc[s][0][1]);
                        acc[s][1][0] = fmaf(w1, y0, acc[s][1][0]);
                        acc[s][1][1] = fmaf(w1, y1, acc[s][1][1]);
                    }
                }
            }
        }
    }

    // ---- epilogue: SO(3)-grid + self-normalized pooling (2 e x 2 z) ----
    const float wi0 = w_i[0], wi1 = w_i[1], wi2 = w_i[2];
    float num[2][2], den[2][2];
    #pragma unroll
    for (int ee = 0; ee < 2; ++ee) { num[ee][0] = num[ee][1] = 0.f; den[ee][0] = den[ee][1] = 0.f; }
    #pragma unroll
    for (int q = 0; q < 27; ++q) {
        const float wl = ((q / 3) % 3 == 0) ? wi0 : (((q / 3) % 3 == 1) ? wi1 : wi2);
        float gv[10];
        #pragma unroll
        for (int s = 0; s < 10; ++s) gv[s] = g[q * 10 + s];  // uniform -> s_load
        #pragma unroll
        for (int ee = 0; ee < 2; ++ee) {
            #pragma unroll
            for (int zi = 0; zi < 2; ++zi) {
                float v = 0.f;
                #pragma unroll
                for (int s = 0; s < 10; ++s) v = fmaf(acc[s][ee][zi], gv[s], v);
                v = fmaxf(v, 0.f);
                den[ee][zi] = fmaf(v, wl, den[ee][zi]);
                num[ee][zi] = fmaf(v * v, wl, num[ee][zi]);
            }
        }
    }
    #pragma unroll
    for (int ee = 0; ee < 2; ++ee) {
        const int e = 2 * c_e + ee;
        const float bz = bias[e];
        float* op = out + (((bb * 16 + e) * 36 + xo) * 36 + (yoq * 4 + c_yo)) * 36
                        + zs * 12 + 2 * c_zt;
        *(float2*)op = make_float2(num[ee][0] / (den[ee][0] + 1e-16f) + bz,
                                   num[ee][1] / (den[ee][1] + 1e-16f) + bz);
    }
}

extern "C" void kernel_launch(void* const* d_in, const int* in_sizes, int n_in,
                              void* d_out, int out_size, void* d_ws, size_t ws_size,
                              hipStream_t stream) {
    const float* x          = (const float*)d_in[0];
    const float* weight     = (const float*)d_in[1];
    const float* zeroweight = (const float*)d_in[2];
    const float* bias       = (const float*)d_in[3];
    const float* g          = (const float*)d_in[4];
    const float* w_i        = (const float*)d_in[5];
    const float* bf         = (const float*)d_in[6];
    float* outp = (float*)d_out;

    float* W2  = (float*)d_ws;            // 10240 f32
    float* TAB = (float*)d_ws + 10240;    // 800 f32 (CT2 layout)

    prep_kernel<<<44, 256, 0, stream>>>(weight, zeroweight, bf, W2, TAB);
    // 1944 blocks = 36 xo * 9 yoq * 3 zs * 2 b, XCD-swizzled in-kernel
    fused_kernel<<<1944, 192, 0, stream>>>(x, W2, TAB, g, w_i, bias, outp);
}